// Round 1
// baseline (1182.206 us; speedup 1.0000x reference)
//
#include <hip/hip_runtime.h>
#include <hip/hip_bf16.h>
#include <math.h>

#define N_NODES 100000
#define N_EDGES 1600000
#define IN_DIM  768
#define HIDDEN  256

// ---- ws layout (bytes), all offsets 16B-aligned ----
#define H_OFF    0ull                  // float h' [N_NODES][HIDDEN]   102,400,000 B
#define ADJ_OFF  102400000ull          // int adj [N_EDGES]              6,400,000 B
#define RS_OFF   108800000ull          // int row_start [N_NODES+1]        400,004 B
#define CUR_OFF  109200016ull          // int cursor [N_NODES]             400,000 B
#define DEG_OFF  109600016ull          // int deg [N_NODES]                400,000 B
#define DINV_OFF 110000016ull          // float dinv [N_NODES]             400,000 B
#define W1T_OFF  110400016ull          // bf16 W1t [HIDDEN][IN_DIM]        393,216 B
// total ~110.8 MB

typedef short  bf16x8 __attribute__((ext_vector_type(8)));
typedef float  fp32x4 __attribute__((ext_vector_type(4)));

__device__ inline short f2bf(float f) {
    union { float f; unsigned u; } c; c.f = f;
    unsigned u = c.u;
    unsigned r = u + 0x7FFFu + ((u >> 16) & 1u);   // RNE
    return (short)(r >> 16);
}

// ---------------- init: zero deg + cursor ----------------
__global__ void init_kernel(int* __restrict__ deg, int* __restrict__ cursor) {
    int i = blockIdx.x * blockDim.x + threadIdx.x;
    if (i < N_NODES) { deg[i] = 0; cursor[i] = 0; }
}

// ---------------- W1 -> W1t (bf16, [HIDDEN][IN_DIM]) ----------------
__global__ void w1t_kernel(const float* __restrict__ w1, short* __restrict__ w1t) {
    int i = blockIdx.x * blockDim.x + threadIdx.x;
    if (i < HIDDEN * IN_DIM) {
        int n = i / IN_DIM, k = i % IN_DIM;
        w1t[i] = f2bf(w1[(size_t)k * HIDDEN + n]);
    }
}

// ---------------- count in-degree (real edges only) ----------------
__global__ void count_kernel(const int* __restrict__ dst, int* __restrict__ deg) {
    int e = blockIdx.x * blockDim.x + threadIdx.x;
    if (e < N_EDGES) atomicAdd(&deg[dst[e]], 1);
}

// ---------------- exclusive scan + dinv (single block of 1024) ----------------
__global__ __launch_bounds__(1024) void scan_kernel(const int* __restrict__ deg,
                                                    int* __restrict__ row_start,
                                                    float* __restrict__ dinv) {
    __shared__ int partial[1024];
    const int CHUNK = 98;  // 98*1024 = 100352 >= 100000
    int tid = threadIdx.x;
    int base = tid * CHUNK;
    int sum = 0;
    for (int i = 0; i < CHUNK; i++) {
        int idx = base + i;
        if (idx < N_NODES) sum += deg[idx];
    }
    partial[tid] = sum;
    __syncthreads();
    for (int off = 1; off < 1024; off <<= 1) {
        int t = (tid >= off) ? partial[tid - off] : 0;
        __syncthreads();
        partial[tid] += t;
        __syncthreads();
    }
    int run = (tid == 0) ? 0 : partial[tid - 1];
    for (int i = 0; i < CHUNK; i++) {
        int idx = base + i;
        if (idx < N_NODES) {
            row_start[idx] = run;
            int d = deg[idx];
            run += d;
            dinv[idx] = rsqrtf((float)(d + 1));  // +1 self loop
        }
    }
    if (tid == 1023) row_start[N_NODES] = partial[1023];
}

// ---------------- fill CSR adjacency (src list grouped by dst) ----------------
__global__ void fill_kernel(const int* __restrict__ src, const int* __restrict__ dst,
                            const int* __restrict__ row_start, int* __restrict__ cursor,
                            int* __restrict__ adj) {
    int e = blockIdx.x * blockDim.x + threadIdx.x;
    if (e < N_EDGES) {
        int d = dst[e];
        int p = row_start[d] + atomicAdd(&cursor[d], 1);
        adj[p] = src[e];
    }
}

// ---------------- GEMM1: h'[r] = dinv[r] * (x[r] @ W1), bf16 MFMA ----------------
// 128x128 output tile, BK=32, 4 waves each computing a 64x64 quadrant (4x4 MFMA tiles).
__global__ __launch_bounds__(256) void gemm1_kernel(const float* __restrict__ x,
                                                    const short* __restrict__ w1t,
                                                    const float* __restrict__ dinv,
                                                    float* __restrict__ h) {
    __shared__ short a_lds[128][32];   // A tile: rows x k  (bf16)
    __shared__ short b_lds[128][32];   // B tile stored transposed: n x k (bf16)

    const int tid  = threadIdx.x;
    const int lane = tid & 63;
    const int wave = tid >> 6;
    const int wm = (wave >> 1) * 64;
    const int wn = (wave & 1) * 64;
    const int l15 = lane & 15;
    const int q   = lane >> 4;
    const int row0 = blockIdx.x * 128;
    const int col0 = blockIdx.y * 128;

    fp32x4 acc[4][4];
    for (int i = 0; i < 4; i++)
        for (int j = 0; j < 4; j++)
            for (int r = 0; r < 4; r++) acc[i][j][r] = 0.0f;

    for (int k0 = 0; k0 < IN_DIM; k0 += 32) {
        // stage A: 128x32 fp32 -> bf16 (512 slots of 8 elems, 2 per thread)
        for (int i = 0; i < 2; i++) {
            int slot = tid + i * 256;
            int r  = slot >> 2;
            int kk = (slot & 3) * 8;
            int gr = row0 + r;
            bf16x8 bv;
            if (gr < N_NODES) {
                const float* p = x + (size_t)gr * IN_DIM + k0 + kk;
                fp32x4 v0 = *(const fp32x4*)p;
                fp32x4 v1 = *(const fp32x4*)(p + 4);
                bv[0] = f2bf(v0[0]); bv[1] = f2bf(v0[1]);
                bv[2] = f2bf(v0[2]); bv[3] = f2bf(v0[3]);
                bv[4] = f2bf(v1[0]); bv[5] = f2bf(v1[1]);
                bv[6] = f2bf(v1[2]); bv[7] = f2bf(v1[3]);
            } else {
                for (int j = 0; j < 8; j++) bv[j] = 0;
            }
            *(bf16x8*)(&a_lds[r][kk]) = bv;
        }
        // stage B: 128x32 bf16 rows of W1t
        for (int i = 0; i < 2; i++) {
            int slot = tid + i * 256;
            int r  = slot >> 2;
            int kk = (slot & 3) * 8;
            int gn = col0 + r;  // < 256 always
            *(bf16x8*)(&b_lds[r][kk]) =
                *(const bf16x8*)(w1t + (size_t)gn * IN_DIM + k0 + kk);
        }
        __syncthreads();

        bf16x8 af[4], bfr[4];
        for (int mt = 0; mt < 4; mt++)
            af[mt] = *(const bf16x8*)(&a_lds[wm + mt * 16 + l15][q * 8]);
        for (int nt = 0; nt < 4; nt++)
            bfr[nt] = *(const bf16x8*)(&b_lds[wn + nt * 16 + l15][q * 8]);
        for (int mt = 0; mt < 4; mt++)
            for (int nt = 0; nt < 4; nt++)
                acc[mt][nt] = __builtin_amdgcn_mfma_f32_16x16x32_bf16(
                    af[mt], bfr[nt], acc[mt][nt], 0, 0, 0);
        __syncthreads();
    }

    // epilogue: h'[row][col] = dinv[row] * acc
    float dv[4][4];
    for (int mt = 0; mt < 4; mt++)
        for (int r = 0; r < 4; r++) {
            int row = row0 + wm + mt * 16 + q * 4 + r;
            dv[mt][r] = (row < N_NODES) ? dinv[row] : 0.0f;
        }
    for (int mt = 0; mt < 4; mt++) {
        for (int nt = 0; nt < 4; nt++) {
            int col = col0 + wn + nt * 16 + l15;
            for (int r = 0; r < 4; r++) {
                int row = row0 + wm + mt * 16 + q * 4 + r;
                if (row < N_NODES)
                    h[(size_t)row * HIDDEN + col] = dv[mt][r] * acc[mt][nt][r];
            }
        }
    }
}

// ---------------- aggregate + bias + relu + W2 + log_softmax ----------------
// one wave per dst node; lane holds 4 of the 256 hidden channels.
__global__ __launch_bounds__(256) void aggregate_kernel(
    const float* __restrict__ h, const int* __restrict__ adj,
    const int* __restrict__ row_start, const float* __restrict__ dinv,
    const float* __restrict__ b1, const float* __restrict__ w2,
    const float* __restrict__ b2, float* __restrict__ out) {
    const int lane = threadIdx.x & 63;
    const int wave = threadIdx.x >> 6;
    const int v = blockIdx.x * 4 + wave;
    if (v >= N_NODES) return;

    // self-loop term: h'[v] (already dinv[v]*h[v])
    fp32x4 acc = *(const fp32x4*)(h + (size_t)v * HIDDEN + lane * 4);

    int e0 = row_start[v], e1 = row_start[v + 1];
    for (int e = e0; e < e1; e += 64) {
        int cnt = min(64, e1 - e);
        int s = (lane < cnt) ? adj[e + lane] : 0;
        for (int i = 0; i < cnt; i++) {
            int srcv = __shfl(s, i, 64);
            acc += *(const fp32x4*)(h + (size_t)srcv * HIDDEN + lane * 4);
        }
    }

    float dvv = dinv[v];
    fp32x4 bb = *(const fp32x4*)(b1 + lane * 4);
    float hr[4];
    for (int j = 0; j < 4; j++) hr[j] = fmaxf(0.0f, dvv * acc[j] + bb[j]);

    float p0 = 0.f, p1 = 0.f, p2 = 0.f;
    for (int j = 0; j < 4; j++) {
        const float* wr = w2 + (size_t)(lane * 4 + j) * 3;
        p0 += hr[j] * wr[0];
        p1 += hr[j] * wr[1];
        p2 += hr[j] * wr[2];
    }
    for (int off = 32; off > 0; off >>= 1) {
        p0 += __shfl_down(p0, off, 64);
        p1 += __shfl_down(p1, off, 64);
        p2 += __shfl_down(p2, off, 64);
    }
    if (lane == 0) {
        p0 += b2[0]; p1 += b2[1]; p2 += b2[2];
        float m = fmaxf(p0, fmaxf(p1, p2));
        float l = logf(expf(p0 - m) + expf(p1 - m) + expf(p2 - m));
        out[(size_t)v * 3 + 0] = p0 - m - l;
        out[(size_t)v * 3 + 1] = p1 - m - l;
        out[(size_t)v * 3 + 2] = p2 - m - l;
    }
}

extern "C" void kernel_launch(void* const* d_in, const int* in_sizes, int n_in,
                              void* d_out, int out_size, void* d_ws, size_t ws_size,
                              hipStream_t stream) {
    const float* x    = (const float*)d_in[0];
    const int*   ei   = (const int*)d_in[1];      // [2][N_EDGES]
    const float* W1   = (const float*)d_in[2];
    const float* b1   = (const float*)d_in[3];
    const float* W2   = (const float*)d_in[4];
    const float* b2   = (const float*)d_in[5];
    float* out = (float*)d_out;

    const int* src = ei;
    const int* dst = ei + N_EDGES;

    char* ws = (char*)d_ws;
    float* h_ws      = (float*)(ws + H_OFF);
    int*   adj       = (int*)(ws + ADJ_OFF);
    int*   row_start = (int*)(ws + RS_OFF);
    int*   cursor    = (int*)(ws + CUR_OFF);
    int*   deg       = (int*)(ws + DEG_OFF);
    float* dinv      = (float*)(ws + DINV_OFF);
    short* w1t       = (short*)(ws + W1T_OFF);

    init_kernel<<<(N_NODES + 255) / 256, 256, 0, stream>>>(deg, cursor);
    w1t_kernel<<<(HIDDEN * IN_DIM + 255) / 256, 256, 0, stream>>>(W1, w1t);
    count_kernel<<<(N_EDGES + 255) / 256, 256, 0, stream>>>(dst, deg);
    scan_kernel<<<1, 1024, 0, stream>>>(deg, row_start, dinv);
    fill_kernel<<<(N_EDGES + 255) / 256, 256, 0, stream>>>(src, dst, row_start, cursor, adj);
    gemm1_kernel<<<dim3((N_NODES + 127) / 128, HIDDEN / 128), 256, 0, stream>>>(x, w1t, dinv, h_ws);
    aggregate_kernel<<<N_NODES / 4, 256, 0, stream>>>(h_ws, adj, row_start, dinv, b1, W2, b2, out);
}

// Round 2
// 942.136 us; speedup vs baseline: 1.2548x; 1.2548x over previous
//
#include <hip/hip_runtime.h>
#include <hip/hip_bf16.h>
#include <math.h>

#define N_NODES 100000
#define N_EDGES 1600000
#define IN_DIM  768
#define HIDDEN  256

#define SCAN_B  256
#define N_SBLK  ((N_NODES + SCAN_B - 1) / SCAN_B)   // 391

// ---- ws layout (bytes), all offsets 16B-aligned ----
#define H_OFF    0ull                  // float h' [N_NODES][HIDDEN]   102,400,000 B
#define ADJ_OFF  102400000ull          // int adj [N_EDGES]              6,400,000 B
#define RS_OFF   108800000ull          // int row_start [N_NODES+1]        400,004 B
#define CUR_OFF  109200016ull          // int cursor [N_NODES]             400,000 B
#define DEG_OFF  109600016ull          // int deg [N_NODES]                400,000 B
#define DINV_OFF 110000016ull          // float dinv [N_NODES]             400,000 B
#define W1T_OFF  110400016ull          // bf16 W1t [HIDDEN][IN_DIM]        393,216 B
#define BSUM_OFF 110800016ull          // int bsum [N_SBLK]                  1,564 B
// total ~110.8 MB

typedef short  bf16x8 __attribute__((ext_vector_type(8)));
typedef float  fp32x4 __attribute__((ext_vector_type(4)));

__device__ inline short f2bf(float f) {
    union { float f; unsigned u; } c; c.f = f;
    unsigned u = c.u;
    unsigned r = u + 0x7FFFu + ((u >> 16) & 1u);   // RNE
    return (short)(r >> 16);
}

// ---------------- init: zero deg + cursor ----------------
__global__ void init_kernel(int* __restrict__ deg, int* __restrict__ cursor) {
    int i = blockIdx.x * blockDim.x + threadIdx.x;
    if (i < N_NODES) { deg[i] = 0; cursor[i] = 0; }
}

// ---------------- W1 -> W1t (bf16, [HIDDEN][IN_DIM]) ----------------
__global__ void w1t_kernel(const float* __restrict__ w1, short* __restrict__ w1t) {
    int i = blockIdx.x * blockDim.x + threadIdx.x;
    if (i < HIDDEN * IN_DIM) {
        int n = i / IN_DIM, k = i % IN_DIM;
        w1t[i] = f2bf(w1[(size_t)k * HIDDEN + n]);
    }
}

// ---------------- count in-degree (real edges only) ----------------
__global__ void count_kernel(const int* __restrict__ dst, int* __restrict__ deg) {
    int e = blockIdx.x * blockDim.x + threadIdx.x;
    if (e < N_EDGES) atomicAdd(&deg[dst[e]], 1);
}

// ---------------- scan phase 1: per-block sums ----------------
__global__ __launch_bounds__(SCAN_B) void scan1_kernel(const int* __restrict__ deg,
                                                       int* __restrict__ bsum) {
    int i = blockIdx.x * SCAN_B + threadIdx.x;
    int v = (i < N_NODES) ? deg[i] : 0;
    for (int off = 32; off > 0; off >>= 1) v += __shfl_down(v, off, 64);
    __shared__ int wsum[SCAN_B / 64];
    int lane = threadIdx.x & 63, w = threadIdx.x >> 6;
    if (lane == 0) wsum[w] = v;
    __syncthreads();
    if (threadIdx.x == 0) {
        int s = 0;
        for (int j = 0; j < SCAN_B / 64; j++) s += wsum[j];
        bsum[blockIdx.x] = s;
    }
}

// ---------------- scan phase 2: exclusive-scan the block sums (1 block) ----------------
__global__ __launch_bounds__(512) void scan2_kernel(int* __restrict__ bsum) {
    __shared__ int s[512];
    int tid = threadIdx.x;
    int v = (tid < N_SBLK) ? bsum[tid] : 0;
    s[tid] = v;
    __syncthreads();
    for (int off = 1; off < 512; off <<= 1) {
        int t = (tid >= off) ? s[tid - off] : 0;
        __syncthreads();
        s[tid] += t;
        __syncthreads();
    }
    if (tid < N_SBLK) bsum[tid] = s[tid] - v;   // exclusive
}

// ---------------- scan phase 3: block-local scan + offset; also dinv ----------------
__global__ __launch_bounds__(SCAN_B) void scan3_kernel(const int* __restrict__ deg,
                                                       const int* __restrict__ bsum,
                                                       int* __restrict__ row_start,
                                                       float* __restrict__ dinv) {
    __shared__ int s[SCAN_B];
    int i = blockIdx.x * SCAN_B + threadIdx.x;
    int tid = threadIdx.x;
    int d = (i < N_NODES) ? deg[i] : 0;
    s[tid] = d;
    __syncthreads();
    for (int off = 1; off < SCAN_B; off <<= 1) {
        int t = (tid >= off) ? s[tid - off] : 0;
        __syncthreads();
        s[tid] += t;
        __syncthreads();
    }
    if (i < N_NODES) {
        row_start[i] = bsum[blockIdx.x] + s[tid] - d;   // exclusive
        dinv[i] = rsqrtf((float)(d + 1));               // +1 self loop
        if (i == N_NODES - 1) row_start[N_NODES] = N_EDGES;  // deg sums to N_EDGES
    }
}

// ---------------- fill CSR adjacency (src list grouped by dst) ----------------
__global__ void fill_kernel(const int* __restrict__ src, const int* __restrict__ dst,
                            const int* __restrict__ row_start, int* __restrict__ cursor,
                            int* __restrict__ adj) {
    int e = blockIdx.x * blockDim.x + threadIdx.x;
    if (e < N_EDGES) {
        int d = dst[e];
        int p = row_start[d] + atomicAdd(&cursor[d], 1);
        adj[p] = src[e];
    }
}

// ---------------- GEMM1: h'[r] = dinv[r] * (x[r] @ W1), bf16 MFMA ----------------
// 128x128 output tile, BK=32, 4 waves each computing a 64x64 quadrant (4x4 MFMA tiles).
__global__ __launch_bounds__(256) void gemm1_kernel(const float* __restrict__ x,
                                                    const short* __restrict__ w1t,
                                                    const float* __restrict__ dinv,
                                                    float* __restrict__ h) {
    __shared__ short a_lds[128][32];   // A tile: rows x k  (bf16)
    __shared__ short b_lds[128][32];   // B tile stored transposed: n x k (bf16)

    const int tid  = threadIdx.x;
    const int lane = tid & 63;
    const int wave = tid >> 6;
    const int wm = (wave >> 1) * 64;
    const int wn = (wave & 1) * 64;
    const int l15 = lane & 15;
    const int q   = lane >> 4;
    const int row0 = blockIdx.x * 128;
    const int col0 = blockIdx.y * 128;

    fp32x4 acc[4][4];
    for (int i = 0; i < 4; i++)
        for (int j = 0; j < 4; j++)
            for (int r = 0; r < 4; r++) acc[i][j][r] = 0.0f;

    for (int k0 = 0; k0 < IN_DIM; k0 += 32) {
        // stage A: 128x32 fp32 -> bf16 (512 slots of 8 elems, 2 per thread)
        for (int i = 0; i < 2; i++) {
            int slot = tid + i * 256;
            int r  = slot >> 2;
            int kk = (slot & 3) * 8;
            int gr = row0 + r;
            bf16x8 bv;
            if (gr < N_NODES) {
                const float* p = x + (size_t)gr * IN_DIM + k0 + kk;
                fp32x4 v0 = *(const fp32x4*)p;
                fp32x4 v1 = *(const fp32x4*)(p + 4);
                bv[0] = f2bf(v0[0]); bv[1] = f2bf(v0[1]);
                bv[2] = f2bf(v0[2]); bv[3] = f2bf(v0[3]);
                bv[4] = f2bf(v1[0]); bv[5] = f2bf(v1[1]);
                bv[6] = f2bf(v1[2]); bv[7] = f2bf(v1[3]);
            } else {
                for (int j = 0; j < 8; j++) bv[j] = 0;
            }
            *(bf16x8*)(&a_lds[r][kk]) = bv;
        }
        // stage B: 128x32 bf16 rows of W1t
        for (int i = 0; i < 2; i++) {
            int slot = tid + i * 256;
            int r  = slot >> 2;
            int kk = (slot & 3) * 8;
            int gn = col0 + r;  // < 256 always
            *(bf16x8*)(&b_lds[r][kk]) =
                *(const bf16x8*)(w1t + (size_t)gn * IN_DIM + k0 + kk);
        }
        __syncthreads();

        bf16x8 af[4], bfr[4];
        for (int mt = 0; mt < 4; mt++)
            af[mt] = *(const bf16x8*)(&a_lds[wm + mt * 16 + l15][q * 8]);
        for (int nt = 0; nt < 4; nt++)
            bfr[nt] = *(const bf16x8*)(&b_lds[wn + nt * 16 + l15][q * 8]);
        for (int mt = 0; mt < 4; mt++)
            for (int nt = 0; nt < 4; nt++)
                acc[mt][nt] = __builtin_amdgcn_mfma_f32_16x16x32_bf16(
                    af[mt], bfr[nt], acc[mt][nt], 0, 0, 0);
        __syncthreads();
    }

    // epilogue: h'[row][col] = dinv[row] * acc
    float dv[4][4];
    for (int mt = 0; mt < 4; mt++)
        for (int r = 0; r < 4; r++) {
            int row = row0 + wm + mt * 16 + q * 4 + r;
            dv[mt][r] = (row < N_NODES) ? dinv[row] : 0.0f;
        }
    for (int mt = 0; mt < 4; mt++) {
        for (int nt = 0; nt < 4; nt++) {
            int col = col0 + wn + nt * 16 + l15;
            for (int r = 0; r < 4; r++) {
                int row = row0 + wm + mt * 16 + q * 4 + r;
                if (row < N_NODES)
                    h[(size_t)row * HIDDEN + col] = dv[mt][r] * acc[mt][nt][r];
            }
        }
    }
}

// ---------------- aggregate + bias + relu + W2 + log_softmax ----------------
// one wave per dst node; lane holds 4 of the 256 hidden channels.
__global__ __launch_bounds__(256) void aggregate_kernel(
    const float* __restrict__ h, const int* __restrict__ adj,
    const int* __restrict__ row_start, const float* __restrict__ dinv,
    const float* __restrict__ b1, const float* __restrict__ w2,
    const float* __restrict__ b2, float* __restrict__ out) {
    const int lane = threadIdx.x & 63;
    const int wave = threadIdx.x >> 6;
    const int v = blockIdx.x * 4 + wave;
    if (v >= N_NODES) return;

    // self-loop term: h'[v] (already dinv[v]*h[v])
    fp32x4 acc = *(const fp32x4*)(h + (size_t)v * HIDDEN + lane * 4);

    int e0 = row_start[v], e1 = row_start[v + 1];
    for (int e = e0; e < e1; e += 64) {
        int cnt = min(64, e1 - e);
        int s = (lane < cnt) ? adj[e + lane] : 0;
        for (int i = 0; i < cnt; i++) {
            int srcv = __shfl(s, i, 64);
            acc += *(const fp32x4*)(h + (size_t)srcv * HIDDEN + lane * 4);
        }
    }

    float dvv = dinv[v];
    fp32x4 bb = *(const fp32x4*)(b1 + lane * 4);
    float hr[4];
    for (int j = 0; j < 4; j++) hr[j] = fmaxf(0.0f, dvv * acc[j] + bb[j]);

    float p0 = 0.f, p1 = 0.f, p2 = 0.f;
    for (int j = 0; j < 4; j++) {
        const float* wr = w2 + (size_t)(lane * 4 + j) * 3;
        p0 += hr[j] * wr[0];
        p1 += hr[j] * wr[1];
        p2 += hr[j] * wr[2];
    }
    for (int off = 32; off > 0; off >>= 1) {
        p0 += __shfl_down(p0, off, 64);
        p1 += __shfl_down(p1, off, 64);
        p2 += __shfl_down(p2, off, 64);
    }
    if (lane == 0) {
        p0 += b2[0]; p1 += b2[1]; p2 += b2[2];
        float m = fmaxf(p0, fmaxf(p1, p2));
        float l = logf(expf(p0 - m) + expf(p1 - m) + expf(p2 - m));
        out[(size_t)v * 3 + 0] = p0 - m - l;
        out[(size_t)v * 3 + 1] = p1 - m - l;
        out[(size_t)v * 3 + 2] = p2 - m - l;
    }
}

extern "C" void kernel_launch(void* const* d_in, const int* in_sizes, int n_in,
                              void* d_out, int out_size, void* d_ws, size_t ws_size,
                              hipStream_t stream) {
    const float* x    = (const float*)d_in[0];
    const int*   ei   = (const int*)d_in[1];      // [2][N_EDGES]
    const float* W1   = (const float*)d_in[2];
    const float* b1   = (const float*)d_in[3];
    const float* W2   = (const float*)d_in[4];
    const float* b2   = (const float*)d_in[5];
    float* out = (float*)d_out;

    const int* src = ei;
    const int* dst = ei + N_EDGES;

    char* ws = (char*)d_ws;
    float* h_ws      = (float*)(ws + H_OFF);
    int*   adj       = (int*)(ws + ADJ_OFF);
    int*   row_start = (int*)(ws + RS_OFF);
    int*   cursor    = (int*)(ws + CUR_OFF);
    int*   deg       = (int*)(ws + DEG_OFF);
    float* dinv      = (float*)(ws + DINV_OFF);
    short* w1t       = (short*)(ws + W1T_OFF);
    int*   bsum      = (int*)(ws + BSUM_OFF);

    init_kernel<<<(N_NODES + 255) / 256, 256, 0, stream>>>(deg, cursor);
    w1t_kernel<<<(HIDDEN * IN_DIM + 255) / 256, 256, 0, stream>>>(W1, w1t);
    count_kernel<<<(N_EDGES + 255) / 256, 256, 0, stream>>>(dst, deg);
    scan1_kernel<<<N_SBLK, SCAN_B, 0, stream>>>(deg, bsum);
    scan2_kernel<<<1, 512, 0, stream>>>(bsum);
    scan3_kernel<<<N_SBLK, SCAN_B, 0, stream>>>(deg, bsum, row_start, dinv);
    fill_kernel<<<(N_EDGES + 255) / 256, 256, 0, stream>>>(src, dst, row_start, cursor, adj);
    gemm1_kernel<<<dim3((N_NODES + 127) / 128, HIDDEN / 128), 256, 0, stream>>>(x, w1t, dinv, h_ws);
    aggregate_kernel<<<N_NODES / 4, 256, 0, stream>>>(h_ws, adj, row_start, dinv, b1, W2, b2, out);
}

// Round 3
// 771.656 us; speedup vs baseline: 1.5320x; 1.2209x over previous
//
#include <hip/hip_runtime.h>
#include <hip/hip_bf16.h>
#include <math.h>

#define N_NODES 100000
#define N_EDGES 1600000
#define IN_DIM  768
#define HIDDEN  256

#define SCAN_B  256
#define N_SBLK  ((N_NODES + SCAN_B - 1) / SCAN_B)   // 391

// ---- ws layout (bytes), all offsets 16B-aligned ----
#define H_OFF    0ull                  // bf16 h' [N_NODES][HIDDEN]     51,200,000 B
#define ADJ_OFF  51200000ull           // int adj [N_EDGES]              6,400,000 B
#define RS_OFF   57600000ull           // int row_start [N_NODES+1]        400,004 B
#define CUR_OFF  58000016ull           // int cursor [N_NODES]             400,000 B
#define DEG_OFF  58400016ull           // int deg [N_NODES]                400,000 B
#define DINV_OFF 58800016ull           // float dinv [N_NODES]             400,000 B
#define W1T_OFF  59200016ull           // bf16 W1t [HIDDEN][IN_DIM]        393,216 B
#define BSUM_OFF 59593232ull           // int bsum [N_SBLK]                  1,564 B
// total ~59.6 MB

typedef short          bf16x8 __attribute__((ext_vector_type(8)));
typedef float          fp32x4 __attribute__((ext_vector_type(4)));
typedef unsigned short u16x4  __attribute__((ext_vector_type(4)));

__device__ inline short f2bf(float f) {
    union { float f; unsigned u; } c; c.f = f;
    unsigned u = c.u;
    unsigned r = u + 0x7FFFu + ((u >> 16) & 1u);   // RNE
    return (short)(r >> 16);
}

__device__ inline fp32x4 bf4_to_f4(u16x4 v) {
    fp32x4 r;
    for (int j = 0; j < 4; j++) {
        union { unsigned u; float f; } c;
        c.u = ((unsigned)v[j]) << 16;
        r[j] = c.f;
    }
    return r;
}

// ---------------- init: zero deg + cursor ----------------
__global__ void init_kernel(int* __restrict__ deg, int* __restrict__ cursor) {
    int i = blockIdx.x * blockDim.x + threadIdx.x;
    if (i < N_NODES) { deg[i] = 0; cursor[i] = 0; }
}

// ---------------- W1 -> W1t (bf16, [HIDDEN][IN_DIM]) ----------------
__global__ void w1t_kernel(const float* __restrict__ w1, short* __restrict__ w1t) {
    int i = blockIdx.x * blockDim.x + threadIdx.x;
    if (i < HIDDEN * IN_DIM) {
        int n = i / IN_DIM, k = i % IN_DIM;
        w1t[i] = f2bf(w1[(size_t)k * HIDDEN + n]);
    }
}

// ---------------- count in-degree (real edges only) ----------------
__global__ void count_kernel(const int* __restrict__ dst, int* __restrict__ deg) {
    int e = blockIdx.x * blockDim.x + threadIdx.x;
    if (e < N_EDGES) atomicAdd(&deg[dst[e]], 1);
}

// ---------------- scan phase 1: per-block sums ----------------
__global__ __launch_bounds__(SCAN_B) void scan1_kernel(const int* __restrict__ deg,
                                                       int* __restrict__ bsum) {
    int i = blockIdx.x * SCAN_B + threadIdx.x;
    int v = (i < N_NODES) ? deg[i] : 0;
    for (int off = 32; off > 0; off >>= 1) v += __shfl_down(v, off, 64);
    __shared__ int wsum[SCAN_B / 64];
    int lane = threadIdx.x & 63, w = threadIdx.x >> 6;
    if (lane == 0) wsum[w] = v;
    __syncthreads();
    if (threadIdx.x == 0) {
        int s = 0;
        for (int j = 0; j < SCAN_B / 64; j++) s += wsum[j];
        bsum[blockIdx.x] = s;
    }
}

// ---------------- scan phase 2: exclusive-scan the block sums (1 block) ----------------
__global__ __launch_bounds__(512) void scan2_kernel(int* __restrict__ bsum) {
    __shared__ int s[512];
    int tid = threadIdx.x;
    int v = (tid < N_SBLK) ? bsum[tid] : 0;
    s[tid] = v;
    __syncthreads();
    for (int off = 1; off < 512; off <<= 1) {
        int t = (tid >= off) ? s[tid - off] : 0;
        __syncthreads();
        s[tid] += t;
        __syncthreads();
    }
    if (tid < N_SBLK) bsum[tid] = s[tid] - v;   // exclusive
}

// ---------------- scan phase 3: block-local scan + offset; also dinv ----------------
__global__ __launch_bounds__(SCAN_B) void scan3_kernel(const int* __restrict__ deg,
                                                       const int* __restrict__ bsum,
                                                       int* __restrict__ row_start,
                                                       float* __restrict__ dinv) {
    __shared__ int s[SCAN_B];
    int i = blockIdx.x * SCAN_B + threadIdx.x;
    int tid = threadIdx.x;
    int d = (i < N_NODES) ? deg[i] : 0;
    s[tid] = d;
    __syncthreads();
    for (int off = 1; off < SCAN_B; off <<= 1) {
        int t = (tid >= off) ? s[tid - off] : 0;
        __syncthreads();
        s[tid] += t;
        __syncthreads();
    }
    if (i < N_NODES) {
        row_start[i] = bsum[blockIdx.x] + s[tid] - d;   // exclusive
        dinv[i] = rsqrtf((float)(d + 1));               // +1 self loop
        if (i == N_NODES - 1) row_start[N_NODES] = N_EDGES;  // deg sums to N_EDGES
    }
}

// ---------------- fill CSR adjacency (src list grouped by dst) ----------------
__global__ void fill_kernel(const int* __restrict__ src, const int* __restrict__ dst,
                            const int* __restrict__ row_start, int* __restrict__ cursor,
                            int* __restrict__ adj) {
    int e = blockIdx.x * blockDim.x + threadIdx.x;
    if (e < N_EDGES) {
        int d = dst[e];
        int p = row_start[d] + atomicAdd(&cursor[d], 1);
        adj[p] = src[e];
    }
}

// ---------------- GEMM1: h'[r] = bf16(dinv[r] * (x[r] @ W1)) ----------------
// 128x128 tile, BK=32, register double-buffered staging, padded LDS (stride 40
// shorts = 80 B: 16B-aligned, frag-read bank starts cover all 32 banks -> 2-way free).
__global__ __launch_bounds__(256) void gemm1_kernel(const float* __restrict__ x,
                                                    const short* __restrict__ w1t,
                                                    const float* __restrict__ dinv,
                                                    unsigned short* __restrict__ h) {
    __shared__ short a_lds[128][40];   // A tile: rows x k (bf16), padded
    __shared__ short b_lds[128][40];   // B tile: cols x k (bf16), padded

    const int tid  = threadIdx.x;
    const int lane = tid & 63;
    const int wave = tid >> 6;
    const int wm = (wave >> 1) * 64;
    const int wn = (wave & 1) * 64;
    const int l15 = lane & 15;
    const int q   = lane >> 4;
    const int row0 = blockIdx.x * 128;
    const int col0 = blockIdx.y * 128;

    // staging slots: slot0 row = tid>>2, slot1 row = 64 + tid>>2, k-chunk = (tid&3)*8
    const int sr0 = tid >> 2;
    const int sr1 = 64 + (tid >> 2);
    const int skk = (tid & 3) * 8;
    const int gr0 = row0 + sr0;
    const int gr1 = row0 + sr1;
    const float* xp0 = x + (size_t)gr0 * IN_DIM + skk;
    const float* xp1 = x + (size_t)gr1 * IN_DIM + skk;
    const short* wp0 = w1t + (size_t)(col0 + sr0) * IN_DIM + skk;
    const short* wp1 = w1t + (size_t)(col0 + sr1) * IN_DIM + skk;
    const bool ok0 = gr0 < N_NODES;
    const bool ok1 = gr1 < N_NODES;

    fp32x4 acc[4][4];
    for (int i = 0; i < 4; i++)
        for (int j = 0; j < 4; j++)
            for (int r = 0; r < 4; r++) acc[i][j][r] = 0.0f;

    fp32x4 pa0a = {0,0,0,0}, pa0b = {0,0,0,0}, pa1a = {0,0,0,0}, pa1b = {0,0,0,0};
    bf16x8 pb0, pb1;

    // prefetch tile k0=0
    if (ok0) { pa0a = *(const fp32x4*)xp0; pa0b = *(const fp32x4*)(xp0 + 4); }
    if (ok1) { pa1a = *(const fp32x4*)xp1; pa1b = *(const fp32x4*)(xp1 + 4); }
    pb0 = *(const bf16x8*)wp0;
    pb1 = *(const bf16x8*)wp1;

    for (int k0 = 0; k0 < IN_DIM; k0 += 32) {
        // commit prefetched tile to LDS (fp32 -> bf16 convert for A)
        bf16x8 av;
        av[0] = f2bf(pa0a[0]); av[1] = f2bf(pa0a[1]);
        av[2] = f2bf(pa0a[2]); av[3] = f2bf(pa0a[3]);
        av[4] = f2bf(pa0b[0]); av[5] = f2bf(pa0b[1]);
        av[6] = f2bf(pa0b[2]); av[7] = f2bf(pa0b[3]);
        *(bf16x8*)(&a_lds[sr0][skk]) = av;
        av[0] = f2bf(pa1a[0]); av[1] = f2bf(pa1a[1]);
        av[2] = f2bf(pa1a[2]); av[3] = f2bf(pa1a[3]);
        av[4] = f2bf(pa1b[0]); av[5] = f2bf(pa1b[1]);
        av[6] = f2bf(pa1b[2]); av[7] = f2bf(pa1b[3]);
        *(bf16x8*)(&a_lds[sr1][skk]) = av;
        *(bf16x8*)(&b_lds[sr0][skk]) = pb0;
        *(bf16x8*)(&b_lds[sr1][skk]) = pb1;
        __syncthreads();

        // prefetch next tile (overlaps with MFMA below)
        int kn = k0 + 32;
        if (kn < IN_DIM) {
            if (ok0) { pa0a = *(const fp32x4*)(xp0 + kn); pa0b = *(const fp32x4*)(xp0 + kn + 4); }
            if (ok1) { pa1a = *(const fp32x4*)(xp1 + kn); pa1b = *(const fp32x4*)(xp1 + kn + 4); }
            pb0 = *(const bf16x8*)(wp0 + kn);
            pb1 = *(const bf16x8*)(wp1 + kn);
        }

        bf16x8 af[4], bfr[4];
        for (int mt = 0; mt < 4; mt++)
            af[mt] = *(const bf16x8*)(&a_lds[wm + mt * 16 + l15][q * 8]);
        for (int nt = 0; nt < 4; nt++)
            bfr[nt] = *(const bf16x8*)(&b_lds[wn + nt * 16 + l15][q * 8]);
        for (int mt = 0; mt < 4; mt++)
            for (int nt = 0; nt < 4; nt++)
                acc[mt][nt] = __builtin_amdgcn_mfma_f32_16x16x32_bf16(
                    af[mt], bfr[nt], acc[mt][nt], 0, 0, 0);
        __syncthreads();
    }

    // epilogue: h'[row][col] = bf16(dinv[row] * acc)
    float dv[4][4];
    for (int mt = 0; mt < 4; mt++)
        for (int r = 0; r < 4; r++) {
            int row = row0 + wm + mt * 16 + q * 4 + r;
            dv[mt][r] = (row < N_NODES) ? dinv[row] : 0.0f;
        }
    for (int mt = 0; mt < 4; mt++) {
        for (int nt = 0; nt < 4; nt++) {
            int col = col0 + wn + nt * 16 + l15;
            for (int r = 0; r < 4; r++) {
                int row = row0 + wm + mt * 16 + q * 4 + r;
                if (row < N_NODES)
                    h[(size_t)row * HIDDEN + col] =
                        (unsigned short)f2bf(dv[mt][r] * acc[mt][nt][r]);
            }
        }
    }
}

// ---------------- aggregate + bias + relu + W2 + log_softmax ----------------
// one wave per dst node; lane holds 4 of the 256 hidden channels (bf16 h').
// edge loop unrolled x4 with 4 accumulators -> 4 gathers in flight.
__global__ __launch_bounds__(256) void aggregate_kernel(
    const unsigned short* __restrict__ h, const int* __restrict__ adj,
    const int* __restrict__ row_start, const float* __restrict__ dinv,
    const float* __restrict__ b1, const float* __restrict__ w2,
    const float* __restrict__ b2, float* __restrict__ out) {
    const int lane = threadIdx.x & 63;
    const int wave = threadIdx.x >> 6;
    const int v = blockIdx.x * 4 + wave;
    if (v >= N_NODES) return;

    const size_t loff = (size_t)lane * 4;

    // self-loop term: h'[v] (already dinv[v]*h[v])
    fp32x4 a0 = bf4_to_f4(*(const u16x4*)(h + (size_t)v * HIDDEN + loff));
    fp32x4 a1 = {0,0,0,0}, a2 = {0,0,0,0}, a3 = {0,0,0,0};

    int e0 = row_start[v], e1 = row_start[v + 1];
    for (int e = e0; e < e1; e += 64) {
        int cnt = min(64, e1 - e);
        int s = (lane < cnt) ? adj[e + lane] : 0;
        int i = 0;
        for (; i + 4 <= cnt; i += 4) {
            int s0 = __shfl(s, i,     64);
            int s1 = __shfl(s, i + 1, 64);
            int s2 = __shfl(s, i + 2, 64);
            int s3 = __shfl(s, i + 3, 64);
            u16x4 r0 = *(const u16x4*)(h + (size_t)s0 * HIDDEN + loff);
            u16x4 r1 = *(const u16x4*)(h + (size_t)s1 * HIDDEN + loff);
            u16x4 r2 = *(const u16x4*)(h + (size_t)s2 * HIDDEN + loff);
            u16x4 r3 = *(const u16x4*)(h + (size_t)s3 * HIDDEN + loff);
            a0 += bf4_to_f4(r0);
            a1 += bf4_to_f4(r1);
            a2 += bf4_to_f4(r2);
            a3 += bf4_to_f4(r3);
        }
        for (; i < cnt; i++) {
            int si = __shfl(s, i, 64);
            a0 += bf4_to_f4(*(const u16x4*)(h + (size_t)si * HIDDEN + loff));
        }
    }
    fp32x4 acc = (a0 + a1) + (a2 + a3);

    float dvv = dinv[v];
    fp32x4 bb = *(const fp32x4*)(b1 + loff);
    float hr[4];
    for (int j = 0; j < 4; j++) hr[j] = fmaxf(0.0f, dvv * acc[j] + bb[j]);

    float p0 = 0.f, p1 = 0.f, p2 = 0.f;
    for (int j = 0; j < 4; j++) {
        const float* wr = w2 + (size_t)(lane * 4 + j) * 3;
        p0 += hr[j] * wr[0];
        p1 += hr[j] * wr[1];
        p2 += hr[j] * wr[2];
    }
    for (int off = 32; off > 0; off >>= 1) {
        p0 += __shfl_down(p0, off, 64);
        p1 += __shfl_down(p1, off, 64);
        p2 += __shfl_down(p2, off, 64);
    }
    if (lane == 0) {
        p0 += b2[0]; p1 += b2[1]; p2 += b2[2];
        float m = fmaxf(p0, fmaxf(p1, p2));
        float l = logf(expf(p0 - m) + expf(p1 - m) + expf(p2 - m));
        out[(size_t)v * 3 + 0] = p0 - m - l;
        out[(size_t)v * 3 + 1] = p1 - m - l;
        out[(size_t)v * 3 + 2] = p2 - m - l;
    }
}

extern "C" void kernel_launch(void* const* d_in, const int* in_sizes, int n_in,
                              void* d_out, int out_size, void* d_ws, size_t ws_size,
                              hipStream_t stream) {
    const float* x    = (const float*)d_in[0];
    const int*   ei   = (const int*)d_in[1];      // [2][N_EDGES]
    const float* W1   = (const float*)d_in[2];
    const float* b1   = (const float*)d_in[3];
    const float* W2   = (const float*)d_in[4];
    const float* b2   = (const float*)d_in[5];
    float* out = (float*)d_out;

    const int* src = ei;
    const int* dst = ei + N_EDGES;

    char* ws = (char*)d_ws;
    unsigned short* h_ws = (unsigned short*)(ws + H_OFF);
    int*   adj       = (int*)(ws + ADJ_OFF);
    int*   row_start = (int*)(ws + RS_OFF);
    int*   cursor    = (int*)(ws + CUR_OFF);
    int*   deg       = (int*)(ws + DEG_OFF);
    float* dinv      = (float*)(ws + DINV_OFF);
    short* w1t       = (short*)(ws + W1T_OFF);
    int*   bsum      = (int*)(ws + BSUM_OFF);

    init_kernel<<<(N_NODES + 255) / 256, 256, 0, stream>>>(deg, cursor);
    w1t_kernel<<<(HIDDEN * IN_DIM + 255) / 256, 256, 0, stream>>>(W1, w1t);
    count_kernel<<<(N_EDGES + 255) / 256, 256, 0, stream>>>(dst, deg);
    scan1_kernel<<<N_SBLK, SCAN_B, 0, stream>>>(deg, bsum);
    scan2_kernel<<<1, 512, 0, stream>>>(bsum);
    scan3_kernel<<<N_SBLK, SCAN_B, 0, stream>>>(deg, bsum, row_start, dinv);
    fill_kernel<<<(N_EDGES + 255) / 256, 256, 0, stream>>>(src, dst, row_start, cursor, adj);
    gemm1_kernel<<<dim3((N_NODES + 127) / 128, HIDDEN / 128), 256, 0, stream>>>(x, w1t, dinv, h_ws);
    aggregate_kernel<<<N_NODES / 4, 256, 0, stream>>>(h_ws, adj, row_start, dinv, b1, W2, b2, out);
}